// Round 1
// baseline (188.742 us; speedup 1.0000x reference)
//
#include <hip/hip_runtime.h>

#define CCOL 10

__global__ void zero_kernel(float* out) {
    if (threadIdx.x == 0 && blockIdx.x == 0) out[0] = 0.0f;
}

// One thread per row-PAIR (2 rows * 10 floats = 80 B = 5 aligned float4s).
__global__ __launch_bounds__(256) void ce_kernel(
    const float* __restrict__ x, const float* __restrict__ tgt,
    const float* __restrict__ exp_c, const float* __restrict__ inv_c,
    const float* __restrict__ log_c, const int* __restrict__ iters_p,
    float* __restrict__ out, int npairs, float neg_inv_b)
{
    // Coefficients: uniform addresses -> compiler emits s_load, broadcast free.
    float ec[9], ic[5], lc[9];
#pragma unroll
    for (int i = 0; i < 9; i++) ec[i] = exp_c[i];
#pragma unroll
    for (int i = 0; i < 5; i++) ic[i] = inv_c[i];
#pragma unroll
    for (int i = 0; i < 9; i++) lc[i] = log_c[i];
    const int niter = iters_p[0];

    int tid = blockIdx.x * blockDim.x + threadIdx.x;
    float local = 0.0f;

    if (tid < npairs) {
        const float4* xv = (const float4*)(x   + (size_t)tid * (2 * CCOL));
        const float4* tv = (const float4*)(tgt + (size_t)tid * (2 * CCOL));
        float xr[2 * CCOL], tr[2 * CCOL];
#pragma unroll
        for (int i = 0; i < 5; i++) {
            float4 v = xv[i];
            xr[4 * i + 0] = v.x; xr[4 * i + 1] = v.y;
            xr[4 * i + 2] = v.z; xr[4 * i + 3] = v.w;
        }
#pragma unroll
        for (int i = 0; i < 5; i++) {
            float4 w = tv[i];
            tr[4 * i + 0] = w.x; tr[4 * i + 1] = w.y;
            tr[4 * i + 2] = w.z; tr[4 * i + 3] = w.w;
        }

#pragma unroll
        for (int r = 0; r < 2; r++) {
            float e[CCOL];
            float s = 0.0f;
#pragma unroll
            for (int c = 0; c < CCOL; c++) {
                float xx = xr[r * CCOL + c];
                float v = ec[8];
#pragma unroll
                for (int i = 7; i >= 0; i--) v = fmaf(v, xx, ec[i]);
                e[c] = v;
                s += v;
            }
            // inverse: deg-4 Horner initial guess + Newton-Raphson
            float inv = ic[4];
#pragma unroll
            for (int i = 3; i >= 0; i--) inv = fmaf(inv, s, ic[i]);
            for (int k = 0; k < niter; k++) inv = inv * (2.0f - s * inv);

#pragma unroll
            for (int c = 0; c < CCOL; c++) {
                float sm = e[c] * inv;
                float v = lc[8];
#pragma unroll
                for (int i = 7; i >= 0; i--) v = fmaf(v, sm, lc[i]);
                local = fmaf(tr[r * CCOL + c], v, local);
            }
        }
    }

    // wave64 shuffle reduce
#pragma unroll
    for (int off = 32; off > 0; off >>= 1)
        local += __shfl_down(local, off, 64);

    __shared__ float wsum[4];
    int lane = threadIdx.x & 63;
    int wid  = threadIdx.x >> 6;
    if (lane == 0) wsum[wid] = local;
    __syncthreads();
    if (threadIdx.x == 0) {
        float b = wsum[0] + wsum[1] + wsum[2] + wsum[3];
        atomicAdd(out, b * neg_inv_b);   // device-scope by default on CDNA
    }
}

extern "C" void kernel_launch(void* const* d_in, const int* in_sizes, int n_in,
                              void* d_out, int out_size, void* d_ws, size_t ws_size,
                              hipStream_t stream) {
    const float* x  = (const float*)d_in[0];
    const float* t  = (const float*)d_in[1];
    const float* ec = (const float*)d_in[2];
    const float* ic = (const float*)d_in[3];
    const float* lc = (const float*)d_in[4];
    const int*   it = (const int*)d_in[5];
    float* out = (float*)d_out;

    int b_rows = in_sizes[0] / CCOL;      // 2,000,000
    int npairs = b_rows / 2;              // 1,000,000 (B is even)
    float neg_inv_b = -1.0f / (float)b_rows;

    zero_kernel<<<1, 64, 0, stream>>>(out);

    const int threads = 256;
    int blocks = (npairs + threads - 1) / threads;
    ce_kernel<<<blocks, threads, 0, stream>>>(x, t, ec, ic, lc, it, out,
                                              npairs, neg_inv_b);
}